// Round 15
// baseline (396.999 us; speedup 1.0000x reference)
//
#include <hip/hip_runtime.h>
#include <hip/hip_fp16.h>

#define N_NODES 500000
#define N_EDGES 8000000
#define EPSF 1e-8f

#define WIN_SHIFT 11
#define WINDOW 2048
#define NB 245                       // ceil(500000/2048)
#define CHUNK 4000                   // edges per scatter chunk
#define NQ (CHUNK / 4)
#define NCHUNK 2000                  // 8e6 / 4000; divisible by 8 (XCD swizzle)
#define SC_ITEMS 8                   // 256*8 >= NCHUNK

typedef int            v4i __attribute__((ext_vector_type(4)));
typedef float          v4f __attribute__((ext_vector_type(4)));
typedef unsigned short v4h __attribute__((ext_vector_type(4)));
typedef int            v2i __attribute__((ext_vector_type(2)));

struct Accum { double pde_sum, bc_sum, bc_cnt, j1_sum, j2_sum, het_cnt; };

__device__ __forceinline__ unsigned short f2h(float f) {
    return __half_as_ushort(__float2half(f));
}
__device__ __forceinline__ float h2f(unsigned short u) {
    return __half2float(__ushort_as_half(u));
}

// Block-wide f64 sum. Valid on thread 0 only. All threads must call. Supports <=1024 threads.
__device__ double block_reduce(double v) {
    __shared__ double sm[16];
    __syncthreads();
    for (int off = 32; off; off >>= 1) v += __shfl_down(v, off, 64);
    const int lane = threadIdx.x & 63, wid = threadIdx.x >> 6;
    if (lane == 0) sm[wid] = v;
    __syncthreads();
    if (wid == 0) {
        const int nw = blockDim.x >> 6;
        v = (lane < nw) ? sm[lane] : 0.0;
        for (int off = 8; off; off >>= 1) v += __shfl_down(v, off, 64);
    }
    return v;
}

// Exclusive prefix over 256 threads. Caller must __syncthreads() before reusing smw.
__device__ unsigned int block_excl_scan_u32(unsigned int x, unsigned int* smw) {
    const int lane = threadIdx.x & 63, wid = threadIdx.x >> 6;
    unsigned int v = x;
    for (int d = 1; d < 64; d <<= 1) {
        unsigned int t = __shfl_up(v, d, 64);
        if (lane >= d) v += t;
    }
    if (lane == 63) smw[wid] = v;
    __syncthreads();
    unsigned int base = 0;
    for (int w = 0; w < wid; ++w) base += smw[w];
    return base + v - x;
}

// Packed endpoint tables (2 MB each, L2-resident):
// Tsrc[i] = uh | (j1h << 16); Tdst[i] = uh | (szh << 16). szh kept for node passes.
__global__ void prep(const float* __restrict__ x, const float* __restrict__ u,
                     const float* __restrict__ j1,
                     unsigned int* __restrict__ Tsrc, unsigned int* __restrict__ Tdst,
                     unsigned short* __restrict__ szh) {
    const int stride = gridDim.x * blockDim.x;
    for (int i = blockIdx.x * blockDim.x + threadIdx.x; i < N_NODES; i += stride) {
        const float z = x[4 * i + 3];
        const unsigned int uhb = f2h(u[i]);
        const unsigned short sb = f2h((float)(z > 0.f) - (float)(z < 0.f));
        Tsrc[i] = uhb | ((unsigned int)f2h(j1[i]) << 16);
        Tdst[i] = uhb | ((unsigned int)sb << 16);
        szh[i]  = sb;
    }
}

// per-chunk bucket histogram + per-chunk het count.
__global__ void k_hist(const v4i* __restrict__ row4, const v4i* __restrict__ attr4,
                       unsigned int* __restrict__ histC,
                       unsigned int* __restrict__ hist_het) {
    __shared__ unsigned int h[NB];
    __shared__ unsigned int hh;
    for (int i = threadIdx.x; i < NB; i += blockDim.x) h[i] = 0;
    if (threadIdx.x == 0) hh = 0;
    __syncthreads();
    const int ch = blockIdx.x;
    unsigned int my = 0;
    for (int q = threadIdx.x; q < NQ; q += blockDim.x) {
        const v4i r = __builtin_nontemporal_load(&row4[ch * NQ + q]);
        const v4i a = __builtin_nontemporal_load(&attr4[ch * NQ + q]);
        atomicAdd(&h[r[0] >> WIN_SHIFT], 1u);
        atomicAdd(&h[r[1] >> WIN_SHIFT], 1u);
        atomicAdd(&h[r[2] >> WIN_SHIFT], 1u);
        atomicAdd(&h[r[3] >> WIN_SHIFT], 1u);
        my += (a[0] == 1) + (a[1] == 1) + (a[2] == 1) + (a[3] == 1);
    }
    if (my) atomicAdd(&hh, my);
    __syncthreads();
    for (int i = threadIdx.x; i < NB; i += blockDim.x)
        histC[(size_t)ch * NB + i] = h[i];
    if (threadIdx.x == 0) hist_het[ch] = hh;
}

// per-bucket exclusive scan across chunks.
__global__ void k_scan1(const unsigned int* __restrict__ histC,
                        unsigned int* __restrict__ scannedB,
                        unsigned int* __restrict__ total) {
    __shared__ unsigned int v[NCHUNK];
    __shared__ unsigned int smw[4];
    const int b = blockIdx.x;
    for (int i = threadIdx.x; i < NCHUNK; i += blockDim.x)
        v[i] = histC[(size_t)i * NB + b];
    __syncthreads();
    const int i0 = threadIdx.x * SC_ITEMS;
    unsigned int s = 0;
    for (int k = 0; k < SC_ITEMS; ++k) { const int i = i0 + k; if (i < NCHUNK) s += v[i]; }
    const unsigned int ex = block_excl_scan_u32(s, smw);
    if (threadIdx.x == blockDim.x - 1) {
        total[b] = ex + s;
        scannedB[(size_t)b * (NCHUNK + 1) + NCHUNK] = ex + s;
    }
    unsigned int run = ex;
    for (int k = 0; k < SC_ITEMS; ++k) {
        const int i = i0 + k;
        if (i < NCHUNK) { scannedB[(size_t)b * (NCHUNK + 1) + i] = run; run += v[i]; }
    }
}

// exclusive scan of per-chunk het counts -> hetbase[0..NCHUNK] (last = total). 1 block.
__global__ void k_scanhet(const unsigned int* __restrict__ hist_het,
                          unsigned int* __restrict__ hetbase) {
    __shared__ unsigned int v[NCHUNK];
    __shared__ unsigned int smw[4];
    for (int i = threadIdx.x; i < NCHUNK; i += blockDim.x) v[i] = hist_het[i];
    __syncthreads();
    const int i0 = threadIdx.x * SC_ITEMS;
    unsigned int s = 0;
    for (int k = 0; k < SC_ITEMS; ++k) { const int i = i0 + k; if (i < NCHUNK) s += v[i]; }
    const unsigned int ex = block_excl_scan_u32(s, smw);
    if (threadIdx.x == blockDim.x - 1) hetbase[NCHUNK] = ex + s;
    unsigned int run = ex;
    for (int k = 0; k < SC_ITEMS; ++k) {
        const int i = i0 + k;
        if (i < NCHUNK) { hetbase[i] = run; run += v[i]; }
    }
}

// tiled transpose: scannedC[ch][b] = scannedB[b][ch].
__global__ void k_tr(const unsigned int* __restrict__ in, unsigned int* __restrict__ out) {
    __shared__ unsigned int t[32][33];
    const int ch0 = blockIdx.x * 32, b0 = blockIdx.y * 32;
    const int tx = threadIdx.x & 31, ty0 = threadIdx.x >> 5;
    for (int j = ty0; j < 32; j += 8) {
        const int b = b0 + j, ch = ch0 + tx;
        if (b < NB && ch < NCHUNK + 1) t[j][tx] = in[(size_t)b * (NCHUNK + 1) + ch];
    }
    __syncthreads();
    for (int j = ty0; j < 32; j += 8) {
        const int ch = ch0 + j, b = b0 + tx;
        if (ch < NCHUNK + 1 && b < NB) out[(size_t)ch * NB + b] = t[tx][j];
    }
}

__global__ void k_scan2(const unsigned int* __restrict__ total, unsigned int* __restrict__ baseb) {
    __shared__ unsigned int smw[4];
    const unsigned int x = (threadIdx.x < NB) ? total[threadIdx.x] : 0;
    const unsigned int ex = block_excl_scan_u32(x, smw);
    if (threadIdx.x < NB) baseb[threadIdx.x] = ex;
}

// LDS-staged bucket-sorted scatter + j1 loss + compacted het list.
// XCD-swizzled chunk mapping: each XCD owns a contiguous chunk range so that
// adjacent chunks' run fragments (adjacent in rec) merge in the local L2.
template<int EMIT_HET>
__global__ void __launch_bounds__(256, 4)
k_scatter(const v4i* __restrict__ row4, const v4i* __restrict__ col4,
          const v4i* __restrict__ attr4,
          const v4f* __restrict__ cdx4, const v4f* __restrict__ cdy4,
          const v4f* __restrict__ clap4,
          const unsigned int* __restrict__ Tsrc, const unsigned int* __restrict__ Tdst,
          const unsigned int* __restrict__ baseb,
          const unsigned int* __restrict__ scannedC,
          const unsigned int* __restrict__ hetbase,
          v4h* __restrict__ rec, v2i* __restrict__ het, Accum* __restrict__ acc) {
    __shared__ int           lcur[NB];
    __shared__ unsigned int  lbase[NB];
    __shared__ unsigned int  gdest[NB];
    __shared__ unsigned int  smw[4];
    __shared__ v4h           o4[CHUNK];
    __shared__ unsigned char obk[CHUNK];
    __shared__ int           hcur;

    // bijective XCD swizzle: NCHUNK % 8 == 0
    const int ch = (blockIdx.x & 7) * (NCHUNK / 8) + (blockIdx.x >> 3);
    unsigned int cnt = 0;
    if (threadIdx.x < NB) {
        const unsigned int s0 = scannedC[(size_t)ch * NB + threadIdx.x];
        const unsigned int s1 = scannedC[(size_t)(ch + 1) * NB + threadIdx.x];
        cnt = s1 - s0;
        gdest[threadIdx.x] = baseb[threadIdx.x] + s0;
        lcur[threadIdx.x] = 0;
    }
    if (EMIT_HET && threadIdx.x == 0) hcur = (int)hetbase[ch];
    const unsigned int exv = block_excl_scan_u32(cnt, smw);
    if (threadIdx.x < NB) lbase[threadIdx.x] = exv;
    __syncthreads();

    double j1s = 0.0;
    int hc = 0;
    for (int q = threadIdx.x; q < NQ; q += blockDim.x) {
        const v4i r4 = __builtin_nontemporal_load(&row4[ch * NQ + q]);
        const v4i c4 = __builtin_nontemporal_load(&col4[ch * NQ + q]);
        const v4i a4 = __builtin_nontemporal_load(&attr4[ch * NQ + q]);
        const v4f cx = __builtin_nontemporal_load(&cdx4[ch * NQ + q]);
        const v4f cy = __builtin_nontemporal_load(&cdy4[ch * NQ + q]);
        const v4f cl = __builtin_nontemporal_load(&clap4[ch * NQ + q]);
#pragma unroll
        for (int k = 0; k < 4; ++k) {
            const int r = r4[k], c = c4[k];
            const unsigned int ts = Tsrc[r];
            const unsigned int td = Tdst[c];
            const float ud = h2f((unsigned short)td) - h2f((unsigned short)ts);
            const int b = r >> WIN_SHIFT;
            const int p = (int)lbase[b] + atomicAdd(&lcur[b], 1);
            v4h rc;
            rc[0] = (unsigned short)(r & (WINDOW - 1));
            rc[1] = f2h(ud * cx[k]);
            rc[2] = f2h(ud * cy[k]);
            rc[3] = f2h(ud * cl[k]);
            o4[p] = rc;
            obk[p] = (unsigned char)b;
            if (a4[k] == 1) {
                const float d = h2f((unsigned short)(td >> 16)) * ud -
                                h2f((unsigned short)(ts >> 16));
                j1s += (double)(d * d);
                hc++;
                if (EMIT_HET) {
                    const int pos = atomicAdd(&hcur, 1);   // LDS counter
                    v2i e; e[0] = r; e[1] = c;
                    __builtin_nontemporal_store(e, &het[pos]);
                }
            }
        }
    }
    __syncthreads();

    for (int i = threadIdx.x; i < CHUNK; i += blockDim.x) {
        const v4h rc = o4[i];
        const int b = obk[i];
        const unsigned int dest = gdest[b] + (unsigned int)(i - (int)lbase[b]);
        __builtin_nontemporal_store(rc, &rec[dest]);
    }

    double t = block_reduce(j1s);
    if (threadIdx.x == 0) atomicAdd(&acc->j1_sum, t);
    t = block_reduce((double)hc);
    if (threadIdx.x == 0) atomicAdd(&acc->het_cnt, t);
}

// Fused per-bucket LDS accumulate at 1024 threads; emit Q with sz in LSBs; pde/bc.
__global__ void __launch_bounds__(1024, 1)
k_acc(const v4h* __restrict__ rec,
      const unsigned int* __restrict__ baseb,
      const unsigned int* __restrict__ total,
      const float* __restrict__ u, const unsigned short* __restrict__ szh,
      const float2* __restrict__ pos2,
      const float* __restrict__ y, const float* __restrict__ source,
      const float* __restrict__ a_p, const float* __restrict__ b_p,
      const float* __restrict__ bm_p, const float* __restrict__ bp_p,
      v4h* __restrict__ Q, Accum* __restrict__ acc) {
    __shared__ float a3[WINDOW * 3];
    for (int i = threadIdx.x; i < WINDOW * 3; i += blockDim.x) a3[i] = 0.f;
    __syncthreads();
    const int b = blockIdx.x;
    const int s = (int)baseb[b];
    const int e = s + (int)total[b];
    for (int i = s + threadIdx.x; i < e; i += blockDim.x) {
        const v4h rc = __builtin_nontemporal_load(&rec[i]);
        const int lr = (int)(rc[0] & (WINDOW - 1)) * 3;
        atomicAdd(&a3[lr + 0], h2f(rc[1]));
        atomicAdd(&a3[lr + 1], h2f(rc[2]));
        atomicAdd(&a3[lr + 2], h2f(rc[3]));
    }
    __syncthreads();
    const float av = a_p[0], bv = b_p[0], bm = bm_p[0], bp = bp_p[0];
    const float ha = 0.5f / (av * av), hb = 0.5f / (bv * bv);
    double pde = 0.0, bcs = 0.0;
    int bcc = 0;
    const int n0 = b << WIN_SHIFT;
    const int n1 = min(n0 + WINDOW, N_NODES);
    for (int i = n0 + threadIdx.x; i < n1; i += blockDim.x) {
        const int l = (i - n0) * 3;
        const float szv = h2f(szh[i]);
        const float beta = (szv < 0.f) ? bm : bp;
        const float2 p = pos2[i];
        v4h qo;
        qo[0] = f2h(p.x * ha);
        qo[1] = f2h(p.y * hb);
        qo[2] = (unsigned short)((f2h(beta * a3[l]) & 0xFFFEu) | (szv < 0.f ? 1u : 0u));
        qo[3] = (unsigned short)((f2h(beta * a3[l + 1]) & 0xFFFEu) | (szv == 0.f ? 1u : 0u));
        Q[i] = qo;
        const float res = -a3[l + 2] - source[i] / beta;
        pde += (double)(res * res);
        if (fabsf(p.x) > 0.99f || fabsf(p.y) > 0.99f) {
            const float d = u[i] - y[i];
            bcs += (double)(d * d);
            bcc++;
        }
    }
    double t = block_reduce(pde);
    if (threadIdx.x == 0) atomicAdd(&acc->pde_sum, t);
    t = block_reduce(bcs);
    if (threadIdx.x == 0) atomicAdd(&acc->bc_sum, t);
    t = block_reduce((double)bcc);
    if (threadIdx.x == 0) atomicAdd(&acc->bc_cnt, t);
}

// j2 over compacted het list: 8B stream + exactly two 8B Q gathers per edge.
__global__ void k_pass2c(const v2i* __restrict__ het,
                         const unsigned int* __restrict__ hetbase,
                         const v4h* __restrict__ Q,
                         const float* __restrict__ c_p,
                         const float* __restrict__ bm_p, const float* __restrict__ bp_p,
                         Accum* __restrict__ acc) {
    const float tgt = 2.f * (c_p[0] * bp_p[0] - bm_p[0]);
    const int tot = (int)hetbase[NCHUNK];
    double j2s = 0.0;
    const int stride = gridDim.x * blockDim.x;
    for (int i = blockIdx.x * blockDim.x + threadIdx.x; i < tot; i += stride) {
        const v2i e = __builtin_nontemporal_load(&het[i]);
        const v4h qr = Q[e[0]];
        const v4h qc = Q[e[1]];
        const float nx = h2f(qr[0]) + h2f(qc[0]);
        const float ny = h2f(qr[1]) + h2f(qc[1]);
        const float nrm = fmaxf(sqrtf(nx * nx + ny * ny), EPSF);
        const float B = ((h2f(qc[2]) - h2f(qr[2])) * nx +
                         (h2f(qc[3]) - h2f(qr[3])) * ny) / nrm;
        const float sz = (qc[3] & 1u) ? 0.f : ((qc[2] & 1u) ? -1.f : 1.f);
        const float d = sz * B - tgt * nrm;
        j2s += (double)(d * d);
    }
    const double t = block_reduce(j2s);
    if (threadIdx.x == 0) atomicAdd(&acc->j2_sum, t);
}

// j2 over raw edges (fallback tier).
__global__ void k_pass2(const v4i* __restrict__ row4, const v4i* __restrict__ col4,
                        const v4i* __restrict__ attr4,
                        const v4h* __restrict__ Q, const unsigned short* __restrict__ szh,
                        const float* __restrict__ c_p,
                        const float* __restrict__ bm_p, const float* __restrict__ bp_p,
                        Accum* __restrict__ acc) {
    const float tgt = 2.f * (c_p[0] * bp_p[0] - bm_p[0]);
    double j2s = 0.0;
    const int stride = gridDim.x * blockDim.x;
    const int NQT = N_EDGES / 4;
    for (int q = blockIdx.x * blockDim.x + threadIdx.x; q < NQT; q += stride) {
        const v4i r4 = __builtin_nontemporal_load(&row4[q]);
        const v4i c4 = __builtin_nontemporal_load(&col4[q]);
        const v4i a4 = __builtin_nontemporal_load(&attr4[q]);
#pragma unroll
        for (int k = 0; k < 4; ++k) {
            if (a4[k] != 1) continue;
            const int r = r4[k], c = c4[k];
            const v4h qr = Q[r];
            const v4h qc = Q[c];
            const float nx = h2f(qr[0]) + h2f(qc[0]);
            const float ny = h2f(qr[1]) + h2f(qc[1]);
            const float nrm = fmaxf(sqrtf(nx * nx + ny * ny), EPSF);
            const float B = ((h2f(qc[2]) - h2f(qr[2])) * nx +
                             (h2f(qc[3]) - h2f(qr[3])) * ny) / nrm;
            const float d = h2f(szh[c]) * B - tgt * nrm;
            j2s += (double)(d * d);
        }
    }
    const double t = block_reduce(j2s);
    if (threadIdx.x == 0) atomicAdd(&acc->j2_sum, t);
}

// ---------------- fallback (small ws): device atomics ----------------
__global__ void fb_edge1(const unsigned int* __restrict__ Tsrc,
                         const unsigned int* __restrict__ Tdst,
                         const float* __restrict__ cdx, const float* __restrict__ cdy,
                         const float* __restrict__ clap,
                         const int* __restrict__ row, const int* __restrict__ col,
                         const int* __restrict__ attr,
                         float* __restrict__ rep, Accum* __restrict__ acc) {
    double j1s = 0.0;
    int hc = 0;
    const int stride = gridDim.x * blockDim.x;
    for (int e = blockIdx.x * blockDim.x + threadIdx.x; e < N_EDGES; e += stride) {
        const int r = row[e], c = col[e];
        const unsigned int ts = Tsrc[r];
        const unsigned int td = Tdst[c];
        const float ud = h2f((unsigned short)td) - h2f((unsigned short)ts);
        atomicAdd(&rep[4 * (size_t)r + 0], ud * cdx[e]);
        atomicAdd(&rep[4 * (size_t)r + 1], ud * cdy[e]);
        atomicAdd(&rep[4 * (size_t)r + 2], ud * clap[e]);
        if (attr[e] == 1) {
            const float d = h2f((unsigned short)(td >> 16)) * ud -
                            h2f((unsigned short)(ts >> 16));
            j1s += (double)(d * d);
            hc++;
        }
    }
    double t = block_reduce(j1s);
    if (threadIdx.x == 0) atomicAdd(&acc->j1_sum, t);
    t = block_reduce((double)hc);
    if (threadIdx.x == 0) atomicAdd(&acc->het_cnt, t);
}

__global__ void fb_reduce(const float4* __restrict__ rep,
                          const float* __restrict__ u, const unsigned short* __restrict__ szh,
                          const float2* __restrict__ pos2,
                          const float* __restrict__ y, const float* __restrict__ source,
                          const float* __restrict__ a_p, const float* __restrict__ b_p,
                          const float* __restrict__ bm_p, const float* __restrict__ bp_p,
                          v4h* __restrict__ Q, Accum* __restrict__ acc) {
    const float av = a_p[0], bv = b_p[0], bm = bm_p[0], bp = bp_p[0];
    const float ha = 0.5f / (av * av), hb = 0.5f / (bv * bv);
    double pde = 0.0, bcs = 0.0;
    int bcc = 0;
    const int stride = gridDim.x * blockDim.x;
    for (int i = blockIdx.x * blockDim.x + threadIdx.x; i < N_NODES; i += stride) {
        const float4 v = rep[i];
        const float szv = h2f(szh[i]);
        const float beta = (szv < 0.f) ? bm : bp;
        const float2 p = pos2[i];
        v4h qo;
        qo[0] = f2h(p.x * ha);
        qo[1] = f2h(p.y * hb);
        qo[2] = (unsigned short)((f2h(beta * v.x) & 0xFFFEu) | (szv < 0.f ? 1u : 0u));
        qo[3] = (unsigned short)((f2h(beta * v.y) & 0xFFFEu) | (szv == 0.f ? 1u : 0u));
        Q[i] = qo;
        const float res = -v.z - source[i] / beta;
        pde += (double)(res * res);
        if (fabsf(p.x) > 0.99f || fabsf(p.y) > 0.99f) {
            const float d = u[i] - y[i];
            bcs += (double)(d * d);
            bcc++;
        }
    }
    double t = block_reduce(pde);
    if (threadIdx.x == 0) atomicAdd(&acc->pde_sum, t);
    t = block_reduce(bcs);
    if (threadIdx.x == 0) atomicAdd(&acc->bc_sum, t);
    t = block_reduce((double)bcc);
    if (threadIdx.x == 0) atomicAdd(&acc->bc_cnt, t);
}

__global__ void finalize(const Accum* __restrict__ acc, float* __restrict__ out) {
    if (threadIdx.x == 0 && blockIdx.x == 0) {
        const double loss_pde = acc->pde_sum / (double)N_NODES;
        const double loss_bc  = acc->bc_sum / fmax(acc->bc_cnt, 1.0);
        const double hc       = fmax(acc->het_cnt, 1.0);
        out[0] = (float)(loss_pde + 100.0 * loss_bc +
                         10.0 * (acc->j1_sum / hc) + 10.0 * (acc->j2_sum / hc));
    }
}

extern "C" void kernel_launch(void* const* d_in, const int* in_sizes, int n_in,
                              void* d_out, int out_size, void* d_ws, size_t ws_size,
                              hipStream_t stream) {
    const float* u_pred = (const float*)d_in[0];
    const float* x      = (const float*)d_in[1];
    const float2* pos2  = (const float2*)d_in[2];
    const float* y      = (const float*)d_in[3];
    const float* source = (const float*)d_in[4];
    const float* j1v    = (const float*)d_in[5];
    const float* cdx    = (const float*)d_in[6];
    const float* cdy    = (const float*)d_in[7];
    const float* clap   = (const float*)d_in[8];
    const float* a_p    = (const float*)d_in[9];
    const float* b_p    = (const float*)d_in[10];
    const float* c_p    = (const float*)d_in[11];
    const float* bm_p   = (const float*)d_in[12];
    const float* bp_p   = (const float*)d_in[13];
    const int* row_idx  = (const int*)d_in[14];
    const int* col_idx  = row_idx + N_EDGES;
    const int* eattr    = (const int*)d_in[15];

    char* base_p = (char*)d_ws;
    size_t off = 0;
    auto alloc = [&](size_t bytes) { void* p = base_p + off; off = (off + bytes + 63) & ~(size_t)63; return p; };

    Accum* acc = (Accum*)alloc(sizeof(Accum));
    unsigned int* Tsrc = (unsigned int*)alloc((size_t)N_NODES * 4);
    unsigned int* Tdst = (unsigned int*)alloc((size_t)N_NODES * 4);
    unsigned short* szh = (unsigned short*)alloc((size_t)N_NODES * 2);
    v4h* Q = (v4h*)alloc((size_t)N_NODES * 8);
    unsigned int* histC    = (unsigned int*)alloc((size_t)(NCHUNK + 1) * NB * 4);
    unsigned int* scannedB = (unsigned int*)alloc((size_t)NB * (NCHUNK + 1) * 4);
    unsigned int* total    = (unsigned int*)alloc(NB * 4);
    unsigned int* baseb    = (unsigned int*)alloc(NB * 4);
    unsigned int* hist_het = (unsigned int*)alloc((size_t)NCHUNK * 4);
    unsigned int* hetbase  = (unsigned int*)alloc((size_t)(NCHUNK + 1) * 4);
    unsigned int* scannedC = histC;          // safe: k_scan1 consumes histC before k_tr writes
    const size_t misc_end = off;
    v4h* rec = (v4h*)alloc((size_t)N_EDGES * 8);
    const size_t need_sort = off;
    v2i* het = (v2i*)alloc((size_t)N_EDGES * 8);   // capacity = all edges: no overflow
    const size_t need_het = off;

    const int threads = 256;
    const int nblocks = (N_NODES + threads - 1) / threads;

    hipMemsetAsync(d_ws, 0, 64, stream);
    prep<<<nblocks, threads, 0, stream>>>(x, u_pred, j1v, Tsrc, Tdst, szh);

    if (ws_size >= need_sort) {
        const bool emit = (ws_size >= need_het);
        k_hist<<<NCHUNK, threads, 0, stream>>>((const v4i*)row_idx, (const v4i*)eattr,
                                               histC, hist_het);
        k_scan1<<<NB, threads, 0, stream>>>(histC, scannedB, total);
        k_scanhet<<<1, threads, 0, stream>>>(hist_het, hetbase);
        {
            dim3 g((NCHUNK + 1 + 31) / 32, (NB + 31) / 32);
            k_tr<<<g, 256, 0, stream>>>(scannedB, scannedC);
        }
        k_scan2<<<1, threads, 0, stream>>>(total, baseb);
        if (emit) {
            k_scatter<1><<<NCHUNK, threads, 0, stream>>>(
                (const v4i*)row_idx, (const v4i*)col_idx, (const v4i*)eattr,
                (const v4f*)cdx, (const v4f*)cdy, (const v4f*)clap,
                Tsrc, Tdst, baseb, scannedC, hetbase, rec, het, acc);
        } else {
            k_scatter<0><<<NCHUNK, threads, 0, stream>>>(
                (const v4i*)row_idx, (const v4i*)col_idx, (const v4i*)eattr,
                (const v4f*)cdx, (const v4f*)cdy, (const v4f*)clap,
                Tsrc, Tdst, baseb, scannedC, hetbase, rec, het, acc);
        }
        k_acc<<<NB, 1024, 0, stream>>>(rec, baseb, total, u_pred, szh, pos2, y, source,
                                       a_p, b_p, bm_p, bp_p, Q, acc);
        if (emit) {
            k_pass2c<<<2048, threads, 0, stream>>>(het, hetbase, Q, c_p, bm_p, bp_p, acc);
        } else {
            k_pass2<<<2048, threads, 0, stream>>>((const v4i*)row_idx, (const v4i*)col_idx,
                                                  (const v4i*)eattr, Q, szh,
                                                  c_p, bm_p, bp_p, acc);
        }
    } else {
        float4* rep = (float4*)(base_p + misc_end);
        hipMemsetAsync(rep, 0, (size_t)N_NODES * 16, stream);
        fb_edge1<<<2048, threads, 0, stream>>>(Tsrc, Tdst, cdx, cdy, clap,
                                               row_idx, col_idx, eattr, (float*)rep, acc);
        fb_reduce<<<nblocks, threads, 0, stream>>>(rep, u_pred, szh, pos2, y, source,
                                                   a_p, b_p, bm_p, bp_p, Q, acc);
        k_pass2<<<2048, threads, 0, stream>>>((const v4i*)row_idx, (const v4i*)col_idx,
                                              (const v4i*)eattr, Q, szh,
                                              c_p, bm_p, bp_p, acc);
    }

    finalize<<<1, 64, 0, stream>>>(acc, (float*)d_out);
}

// Round 16
// 374.729 us; speedup vs baseline: 1.0594x; 1.0594x over previous
//
#include <hip/hip_runtime.h>
#include <hip/hip_fp16.h>

#define N_NODES 500000
#define N_EDGES 8000000
#define EPSF 1e-8f

#define WIN_SHIFT 11
#define WINDOW 2048
#define NB 245                       // ceil(500000/2048)
#define CHUNK 8000                   // edges per scatter chunk (runs avg 32.6)
#define NQ (CHUNK / 4)
#define NCHUNK 1000                  // 8e6 / 8000
#define SC_ITEMS 4                   // 256*4 >= NCHUNK

typedef int            v4i __attribute__((ext_vector_type(4)));
typedef float          v4f __attribute__((ext_vector_type(4)));
typedef unsigned short v4h __attribute__((ext_vector_type(4)));
typedef int            v2i __attribute__((ext_vector_type(2)));

struct Accum { double pde_sum, bc_sum, bc_cnt, j1_sum, j2_sum, het_cnt; };

__device__ __forceinline__ unsigned short f2h(float f) {
    return __half_as_ushort(__float2half(f));
}
__device__ __forceinline__ float h2f(unsigned short u) {
    return __half2float(__ushort_as_half(u));
}

// Block-wide f64 sum. Valid on thread 0 only. All threads must call. Supports <=1024 threads.
__device__ double block_reduce(double v) {
    __shared__ double sm[16];
    __syncthreads();
    for (int off = 32; off; off >>= 1) v += __shfl_down(v, off, 64);
    const int lane = threadIdx.x & 63, wid = threadIdx.x >> 6;
    if (lane == 0) sm[wid] = v;
    __syncthreads();
    if (wid == 0) {
        const int nw = blockDim.x >> 6;
        v = (lane < nw) ? sm[lane] : 0.0;
        for (int off = 8; off; off >>= 1) v += __shfl_down(v, off, 64);
    }
    return v;
}

// Exclusive prefix over 256 threads. Caller must __syncthreads() before reusing smw.
__device__ unsigned int block_excl_scan_u32(unsigned int x, unsigned int* smw) {
    const int lane = threadIdx.x & 63, wid = threadIdx.x >> 6;
    unsigned int v = x;
    for (int d = 1; d < 64; d <<= 1) {
        unsigned int t = __shfl_up(v, d, 64);
        if (lane >= d) v += t;
    }
    if (lane == 63) smw[wid] = v;
    __syncthreads();
    unsigned int base = 0;
    for (int w = 0; w < wid; ++w) base += smw[w];
    return base + v - x;
}

// Packed endpoint tables (2 MB each, L2-resident):
// Tsrc[i] = uh | (j1h << 16); Tdst[i] = uh | (szh << 16). szh kept for node passes.
__global__ void prep(const float* __restrict__ x, const float* __restrict__ u,
                     const float* __restrict__ j1,
                     unsigned int* __restrict__ Tsrc, unsigned int* __restrict__ Tdst,
                     unsigned short* __restrict__ szh) {
    const int stride = gridDim.x * blockDim.x;
    for (int i = blockIdx.x * blockDim.x + threadIdx.x; i < N_NODES; i += stride) {
        const float z = x[4 * i + 3];
        const unsigned int uhb = f2h(u[i]);
        const unsigned short sb = f2h((float)(z > 0.f) - (float)(z < 0.f));
        Tsrc[i] = uhb | ((unsigned int)f2h(j1[i]) << 16);
        Tdst[i] = uhb | ((unsigned int)sb << 16);
        szh[i]  = sb;
    }
}

// per-chunk bucket histogram + per-chunk het count.
__global__ void k_hist(const v4i* __restrict__ row4, const v4i* __restrict__ attr4,
                       unsigned int* __restrict__ histC,
                       unsigned int* __restrict__ hist_het) {
    __shared__ unsigned int h[NB];
    __shared__ unsigned int hh;
    for (int i = threadIdx.x; i < NB; i += blockDim.x) h[i] = 0;
    if (threadIdx.x == 0) hh = 0;
    __syncthreads();
    const int ch = blockIdx.x;
    unsigned int my = 0;
    for (int q = threadIdx.x; q < NQ; q += blockDim.x) {
        const v4i r = __builtin_nontemporal_load(&row4[ch * NQ + q]);
        const v4i a = __builtin_nontemporal_load(&attr4[ch * NQ + q]);
        atomicAdd(&h[r[0] >> WIN_SHIFT], 1u);
        atomicAdd(&h[r[1] >> WIN_SHIFT], 1u);
        atomicAdd(&h[r[2] >> WIN_SHIFT], 1u);
        atomicAdd(&h[r[3] >> WIN_SHIFT], 1u);
        my += (a[0] == 1) + (a[1] == 1) + (a[2] == 1) + (a[3] == 1);
    }
    if (my) atomicAdd(&hh, my);
    __syncthreads();
    for (int i = threadIdx.x; i < NB; i += blockDim.x)
        histC[(size_t)ch * NB + i] = h[i];
    if (threadIdx.x == 0) hist_het[ch] = hh;
}

// per-bucket exclusive scan across chunks.
__global__ void k_scan1(const unsigned int* __restrict__ histC,
                        unsigned int* __restrict__ scannedB,
                        unsigned int* __restrict__ total) {
    __shared__ unsigned int v[NCHUNK];
    __shared__ unsigned int smw[4];
    const int b = blockIdx.x;
    for (int i = threadIdx.x; i < NCHUNK; i += blockDim.x)
        v[i] = histC[(size_t)i * NB + b];
    __syncthreads();
    const int i0 = threadIdx.x * SC_ITEMS;
    unsigned int s = 0;
    for (int k = 0; k < SC_ITEMS; ++k) { const int i = i0 + k; if (i < NCHUNK) s += v[i]; }
    const unsigned int ex = block_excl_scan_u32(s, smw);
    if (threadIdx.x == blockDim.x - 1) {
        total[b] = ex + s;
        scannedB[(size_t)b * (NCHUNK + 1) + NCHUNK] = ex + s;
    }
    unsigned int run = ex;
    for (int k = 0; k < SC_ITEMS; ++k) {
        const int i = i0 + k;
        if (i < NCHUNK) { scannedB[(size_t)b * (NCHUNK + 1) + i] = run; run += v[i]; }
    }
}

// block 0: het scan -> hetbase[0..NCHUNK]; block 1: bucket-base scan -> baseb.
__global__ void k_scan2(const unsigned int* __restrict__ hist_het,
                        const unsigned int* __restrict__ total,
                        unsigned int* __restrict__ hetbase,
                        unsigned int* __restrict__ baseb) {
    __shared__ unsigned int v[NCHUNK];
    __shared__ unsigned int smw[4];
    if (blockIdx.x == 0) {
        for (int i = threadIdx.x; i < NCHUNK; i += blockDim.x) v[i] = hist_het[i];
        __syncthreads();
        const int i0 = threadIdx.x * SC_ITEMS;
        unsigned int s = 0;
        for (int k = 0; k < SC_ITEMS; ++k) { const int i = i0 + k; if (i < NCHUNK) s += v[i]; }
        const unsigned int ex = block_excl_scan_u32(s, smw);
        if (threadIdx.x == blockDim.x - 1) hetbase[NCHUNK] = ex + s;
        unsigned int run = ex;
        for (int k = 0; k < SC_ITEMS; ++k) {
            const int i = i0 + k;
            if (i < NCHUNK) { hetbase[i] = run; run += v[i]; }
        }
    } else {
        const unsigned int x = (threadIdx.x < NB) ? total[threadIdx.x] : 0;
        const unsigned int ex = block_excl_scan_u32(x, smw);
        if (threadIdx.x < NB) baseb[threadIdx.x] = ex;
    }
}

// tiled transpose: scannedC[ch][b] = scannedB[b][ch].
__global__ void k_tr(const unsigned int* __restrict__ in, unsigned int* __restrict__ out) {
    __shared__ unsigned int t[32][33];
    const int ch0 = blockIdx.x * 32, b0 = blockIdx.y * 32;
    const int tx = threadIdx.x & 31, ty0 = threadIdx.x >> 5;
    for (int j = ty0; j < 32; j += 8) {
        const int b = b0 + j, ch = ch0 + tx;
        if (b < NB && ch < NCHUNK + 1) t[j][tx] = in[(size_t)b * (NCHUNK + 1) + ch];
    }
    __syncthreads();
    for (int j = ty0; j < 32; j += 8) {
        const int ch = ch0 + j, b = b0 + tx;
        if (ch < NCHUNK + 1 && b < NB) out[(size_t)ch * NB + b] = t[tx][j];
    }
}

// LDS-staged bucket-sorted scatter + j1 loss + compacted het list (LDS-counter positions).
template<int EMIT_HET>
__global__ void __launch_bounds__(256, 2)
k_scatter(const v4i* __restrict__ row4, const v4i* __restrict__ col4,
          const v4i* __restrict__ attr4,
          const v4f* __restrict__ cdx4, const v4f* __restrict__ cdy4,
          const v4f* __restrict__ clap4,
          const unsigned int* __restrict__ Tsrc, const unsigned int* __restrict__ Tdst,
          const unsigned int* __restrict__ baseb,
          const unsigned int* __restrict__ scannedC,
          const unsigned int* __restrict__ hetbase,
          v4h* __restrict__ rec, v2i* __restrict__ het, Accum* __restrict__ acc) {
    __shared__ int           lcur[NB];
    __shared__ unsigned int  lbase[NB];
    __shared__ unsigned int  gdest[NB];
    __shared__ unsigned int  smw[4];
    __shared__ v4h           o4[CHUNK];
    __shared__ unsigned char obk[CHUNK];
    __shared__ int           hcur;

    const int ch = blockIdx.x;
    unsigned int cnt = 0;
    if (threadIdx.x < NB) {
        const unsigned int s0 = scannedC[(size_t)ch * NB + threadIdx.x];
        const unsigned int s1 = scannedC[(size_t)(ch + 1) * NB + threadIdx.x];
        cnt = s1 - s0;
        gdest[threadIdx.x] = baseb[threadIdx.x] + s0;
        lcur[threadIdx.x] = 0;
    }
    if (EMIT_HET && threadIdx.x == 0) hcur = (int)hetbase[ch];
    const unsigned int exv = block_excl_scan_u32(cnt, smw);
    if (threadIdx.x < NB) lbase[threadIdx.x] = exv;
    __syncthreads();

    double j1s = 0.0;
    int hc = 0;
    for (int q = threadIdx.x; q < NQ; q += blockDim.x) {
        const v4i r4 = __builtin_nontemporal_load(&row4[ch * NQ + q]);
        const v4i c4 = __builtin_nontemporal_load(&col4[ch * NQ + q]);
        const v4i a4 = __builtin_nontemporal_load(&attr4[ch * NQ + q]);
        const v4f cx = __builtin_nontemporal_load(&cdx4[ch * NQ + q]);
        const v4f cy = __builtin_nontemporal_load(&cdy4[ch * NQ + q]);
        const v4f cl = __builtin_nontemporal_load(&clap4[ch * NQ + q]);
#pragma unroll
        for (int k = 0; k < 4; ++k) {
            const int r = r4[k], c = c4[k];
            const unsigned int ts = Tsrc[r];
            const unsigned int td = Tdst[c];
            const float ud = h2f((unsigned short)td) - h2f((unsigned short)ts);
            const int b = r >> WIN_SHIFT;
            const int p = (int)lbase[b] + atomicAdd(&lcur[b], 1);
            v4h rc;
            rc[0] = (unsigned short)(r & (WINDOW - 1));
            rc[1] = f2h(ud * cx[k]);
            rc[2] = f2h(ud * cy[k]);
            rc[3] = f2h(ud * cl[k]);
            o4[p] = rc;
            obk[p] = (unsigned char)b;
            if (a4[k] == 1) {
                const float d = h2f((unsigned short)(td >> 16)) * ud -
                                h2f((unsigned short)(ts >> 16));
                j1s += (double)(d * d);
                hc++;
                if (EMIT_HET) {
                    const int pos = atomicAdd(&hcur, 1);   // LDS counter
                    v2i e; e[0] = r; e[1] = c;
                    __builtin_nontemporal_store(e, &het[pos]);
                }
            }
        }
    }
    __syncthreads();

    for (int i = threadIdx.x; i < CHUNK; i += blockDim.x) {
        const v4h rc = o4[i];
        const int b = obk[i];
        const unsigned int dest = gdest[b] + (unsigned int)(i - (int)lbase[b]);
        __builtin_nontemporal_store(rc, &rec[dest]);
    }

    double t = block_reduce(j1s);
    if (threadIdx.x == 0) atomicAdd(&acc->j1_sum, t);
    t = block_reduce((double)hc);
    if (threadIdx.x == 0) atomicAdd(&acc->het_cnt, t);
}

// Fused per-bucket LDS accumulate at 1024 threads; emit Q with sz in LSBs; pde/bc.
__global__ void __launch_bounds__(1024, 1)
k_acc(const v4h* __restrict__ rec,
      const unsigned int* __restrict__ baseb,
      const unsigned int* __restrict__ total,
      const float* __restrict__ u, const unsigned short* __restrict__ szh,
      const float2* __restrict__ pos2,
      const float* __restrict__ y, const float* __restrict__ source,
      const float* __restrict__ a_p, const float* __restrict__ b_p,
      const float* __restrict__ bm_p, const float* __restrict__ bp_p,
      v4h* __restrict__ Q, Accum* __restrict__ acc) {
    __shared__ float a3[WINDOW * 3];
    for (int i = threadIdx.x; i < WINDOW * 3; i += blockDim.x) a3[i] = 0.f;
    __syncthreads();
    const int b = blockIdx.x;
    const int s = (int)baseb[b];
    const int e = s + (int)total[b];
    for (int i = s + threadIdx.x; i < e; i += blockDim.x) {
        const v4h rc = __builtin_nontemporal_load(&rec[i]);
        const int lr = (int)(rc[0] & (WINDOW - 1)) * 3;
        atomicAdd(&a3[lr + 0], h2f(rc[1]));
        atomicAdd(&a3[lr + 1], h2f(rc[2]));
        atomicAdd(&a3[lr + 2], h2f(rc[3]));
    }
    __syncthreads();
    const float av = a_p[0], bv = b_p[0], bm = bm_p[0], bp = bp_p[0];
    const float ha = 0.5f / (av * av), hb = 0.5f / (bv * bv);
    double pde = 0.0, bcs = 0.0;
    int bcc = 0;
    const int n0 = b << WIN_SHIFT;
    const int n1 = min(n0 + WINDOW, N_NODES);
    for (int i = n0 + threadIdx.x; i < n1; i += blockDim.x) {
        const int l = (i - n0) * 3;
        const float szv = h2f(szh[i]);
        const float beta = (szv < 0.f) ? bm : bp;
        const float2 p = pos2[i];
        v4h qo;
        qo[0] = f2h(p.x * ha);
        qo[1] = f2h(p.y * hb);
        qo[2] = (unsigned short)((f2h(beta * a3[l]) & 0xFFFEu) | (szv < 0.f ? 1u : 0u));
        qo[3] = (unsigned short)((f2h(beta * a3[l + 1]) & 0xFFFEu) | (szv == 0.f ? 1u : 0u));
        Q[i] = qo;
        const float res = -a3[l + 2] - source[i] / beta;
        pde += (double)(res * res);
        if (fabsf(p.x) > 0.99f || fabsf(p.y) > 0.99f) {
            const float d = u[i] - y[i];
            bcs += (double)(d * d);
            bcc++;
        }
    }
    double t = block_reduce(pde);
    if (threadIdx.x == 0) atomicAdd(&acc->pde_sum, t);
    t = block_reduce(bcs);
    if (threadIdx.x == 0) atomicAdd(&acc->bc_sum, t);
    t = block_reduce((double)bcc);
    if (threadIdx.x == 0) atomicAdd(&acc->bc_cnt, t);
}

// j2 over compacted het list: 8B stream + exactly two 8B Q gathers per edge.
__global__ void k_pass2c(const v2i* __restrict__ het,
                         const unsigned int* __restrict__ hetbase,
                         const v4h* __restrict__ Q,
                         const float* __restrict__ c_p,
                         const float* __restrict__ bm_p, const float* __restrict__ bp_p,
                         Accum* __restrict__ acc) {
    const float tgt = 2.f * (c_p[0] * bp_p[0] - bm_p[0]);
    const int tot = (int)hetbase[NCHUNK];
    double j2s = 0.0;
    const int stride = gridDim.x * blockDim.x;
    for (int i = blockIdx.x * blockDim.x + threadIdx.x; i < tot; i += stride) {
        const v2i e = __builtin_nontemporal_load(&het[i]);
        const v4h qr = Q[e[0]];
        const v4h qc = Q[e[1]];
        const float nx = h2f(qr[0]) + h2f(qc[0]);
        const float ny = h2f(qr[1]) + h2f(qc[1]);
        const float nrm = fmaxf(sqrtf(nx * nx + ny * ny), EPSF);
        const float B = ((h2f(qc[2]) - h2f(qr[2])) * nx +
                         (h2f(qc[3]) - h2f(qr[3])) * ny) / nrm;
        const float sz = (qc[3] & 1u) ? 0.f : ((qc[2] & 1u) ? -1.f : 1.f);
        const float d = sz * B - tgt * nrm;
        j2s += (double)(d * d);
    }
    const double t = block_reduce(j2s);
    if (threadIdx.x == 0) atomicAdd(&acc->j2_sum, t);
}

// j2 over raw edges (fallback tier).
__global__ void k_pass2(const v4i* __restrict__ row4, const v4i* __restrict__ col4,
                        const v4i* __restrict__ attr4,
                        const v4h* __restrict__ Q, const unsigned short* __restrict__ szh,
                        const float* __restrict__ c_p,
                        const float* __restrict__ bm_p, const float* __restrict__ bp_p,
                        Accum* __restrict__ acc) {
    const float tgt = 2.f * (c_p[0] * bp_p[0] - bm_p[0]);
    double j2s = 0.0;
    const int stride = gridDim.x * blockDim.x;
    const int NQT = N_EDGES / 4;
    for (int q = blockIdx.x * blockDim.x + threadIdx.x; q < NQT; q += stride) {
        const v4i r4 = __builtin_nontemporal_load(&row4[q]);
        const v4i c4 = __builtin_nontemporal_load(&col4[q]);
        const v4i a4 = __builtin_nontemporal_load(&attr4[q]);
#pragma unroll
        for (int k = 0; k < 4; ++k) {
            if (a4[k] != 1) continue;
            const int r = r4[k], c = c4[k];
            const v4h qr = Q[r];
            const v4h qc = Q[c];
            const float nx = h2f(qr[0]) + h2f(qc[0]);
            const float ny = h2f(qr[1]) + h2f(qc[1]);
            const float nrm = fmaxf(sqrtf(nx * nx + ny * ny), EPSF);
            const float B = ((h2f(qc[2]) - h2f(qr[2])) * nx +
                             (h2f(qc[3]) - h2f(qr[3])) * ny) / nrm;
            const float d = h2f(szh[c]) * B - tgt * nrm;
            j2s += (double)(d * d);
        }
    }
    const double t = block_reduce(j2s);
    if (threadIdx.x == 0) atomicAdd(&acc->j2_sum, t);
}

// ---------------- fallback (small ws): device atomics ----------------
__global__ void fb_edge1(const unsigned int* __restrict__ Tsrc,
                         const unsigned int* __restrict__ Tdst,
                         const float* __restrict__ cdx, const float* __restrict__ cdy,
                         const float* __restrict__ clap,
                         const int* __restrict__ row, const int* __restrict__ col,
                         const int* __restrict__ attr,
                         float* __restrict__ rep, Accum* __restrict__ acc) {
    double j1s = 0.0;
    int hc = 0;
    const int stride = gridDim.x * blockDim.x;
    for (int e = blockIdx.x * blockDim.x + threadIdx.x; e < N_EDGES; e += stride) {
        const int r = row[e], c = col[e];
        const unsigned int ts = Tsrc[r];
        const unsigned int td = Tdst[c];
        const float ud = h2f((unsigned short)td) - h2f((unsigned short)ts);
        atomicAdd(&rep[4 * (size_t)r + 0], ud * cdx[e]);
        atomicAdd(&rep[4 * (size_t)r + 1], ud * cdy[e]);
        atomicAdd(&rep[4 * (size_t)r + 2], ud * clap[e]);
        if (attr[e] == 1) {
            const float d = h2f((unsigned short)(td >> 16)) * ud -
                            h2f((unsigned short)(ts >> 16));
            j1s += (double)(d * d);
            hc++;
        }
    }
    double t = block_reduce(j1s);
    if (threadIdx.x == 0) atomicAdd(&acc->j1_sum, t);
    t = block_reduce((double)hc);
    if (threadIdx.x == 0) atomicAdd(&acc->het_cnt, t);
}

__global__ void fb_reduce(const float4* __restrict__ rep,
                          const float* __restrict__ u, const unsigned short* __restrict__ szh,
                          const float2* __restrict__ pos2,
                          const float* __restrict__ y, const float* __restrict__ source,
                          const float* __restrict__ a_p, const float* __restrict__ b_p,
                          const float* __restrict__ bm_p, const float* __restrict__ bp_p,
                          v4h* __restrict__ Q, Accum* __restrict__ acc) {
    const float av = a_p[0], bv = b_p[0], bm = bm_p[0], bp = bp_p[0];
    const float ha = 0.5f / (av * av), hb = 0.5f / (bv * bv);
    double pde = 0.0, bcs = 0.0;
    int bcc = 0;
    const int stride = gridDim.x * blockDim.x;
    for (int i = blockIdx.x * blockDim.x + threadIdx.x; i < N_NODES; i += stride) {
        const float4 v = rep[i];
        const float szv = h2f(szh[i]);
        const float beta = (szv < 0.f) ? bm : bp;
        const float2 p = pos2[i];
        v4h qo;
        qo[0] = f2h(p.x * ha);
        qo[1] = f2h(p.y * hb);
        qo[2] = (unsigned short)((f2h(beta * v.x) & 0xFFFEu) | (szv < 0.f ? 1u : 0u));
        qo[3] = (unsigned short)((f2h(beta * v.y) & 0xFFFEu) | (szv == 0.f ? 1u : 0u));
        Q[i] = qo;
        const float res = -v.z - source[i] / beta;
        pde += (double)(res * res);
        if (fabsf(p.x) > 0.99f || fabsf(p.y) > 0.99f) {
            const float d = u[i] - y[i];
            bcs += (double)(d * d);
            bcc++;
        }
    }
    double t = block_reduce(pde);
    if (threadIdx.x == 0) atomicAdd(&acc->pde_sum, t);
    t = block_reduce(bcs);
    if (threadIdx.x == 0) atomicAdd(&acc->bc_sum, t);
    t = block_reduce((double)bcc);
    if (threadIdx.x == 0) atomicAdd(&acc->bc_cnt, t);
}

__global__ void finalize(const Accum* __restrict__ acc, float* __restrict__ out) {
    if (threadIdx.x == 0 && blockIdx.x == 0) {
        const double loss_pde = acc->pde_sum / (double)N_NODES;
        const double loss_bc  = acc->bc_sum / fmax(acc->bc_cnt, 1.0);
        const double hc       = fmax(acc->het_cnt, 1.0);
        out[0] = (float)(loss_pde + 100.0 * loss_bc +
                         10.0 * (acc->j1_sum / hc) + 10.0 * (acc->j2_sum / hc));
    }
}

extern "C" void kernel_launch(void* const* d_in, const int* in_sizes, int n_in,
                              void* d_out, int out_size, void* d_ws, size_t ws_size,
                              hipStream_t stream) {
    const float* u_pred = (const float*)d_in[0];
    const float* x      = (const float*)d_in[1];
    const float2* pos2  = (const float2*)d_in[2];
    const float* y      = (const float*)d_in[3];
    const float* source = (const float*)d_in[4];
    const float* j1v    = (const float*)d_in[5];
    const float* cdx    = (const float*)d_in[6];
    const float* cdy    = (const float*)d_in[7];
    const float* clap   = (const float*)d_in[8];
    const float* a_p    = (const float*)d_in[9];
    const float* b_p    = (const float*)d_in[10];
    const float* c_p    = (const float*)d_in[11];
    const float* bm_p   = (const float*)d_in[12];
    const float* bp_p   = (const float*)d_in[13];
    const int* row_idx  = (const int*)d_in[14];
    const int* col_idx  = row_idx + N_EDGES;
    const int* eattr    = (const int*)d_in[15];

    char* base_p = (char*)d_ws;
    size_t off = 0;
    auto alloc = [&](size_t bytes) { void* p = base_p + off; off = (off + bytes + 63) & ~(size_t)63; return p; };

    Accum* acc = (Accum*)alloc(sizeof(Accum));
    unsigned int* Tsrc = (unsigned int*)alloc((size_t)N_NODES * 4);
    unsigned int* Tdst = (unsigned int*)alloc((size_t)N_NODES * 4);
    unsigned short* szh = (unsigned short*)alloc((size_t)N_NODES * 2);
    v4h* Q = (v4h*)alloc((size_t)N_NODES * 8);
    unsigned int* histC    = (unsigned int*)alloc((size_t)(NCHUNK + 1) * NB * 4);
    unsigned int* scannedB = (unsigned int*)alloc((size_t)NB * (NCHUNK + 1) * 4);
    unsigned int* total    = (unsigned int*)alloc(NB * 4);
    unsigned int* baseb    = (unsigned int*)alloc(NB * 4);
    unsigned int* hist_het = (unsigned int*)alloc((size_t)NCHUNK * 4);
    unsigned int* hetbase  = (unsigned int*)alloc((size_t)(NCHUNK + 1) * 4);
    unsigned int* scannedC = histC;          // safe: k_scan1 consumes histC before k_tr writes
    const size_t misc_end = off;
    v4h* rec = (v4h*)alloc((size_t)N_EDGES * 8);
    const size_t need_sort = off;
    v2i* het = (v2i*)alloc((size_t)N_EDGES * 8);   // capacity = all edges: no overflow
    const size_t need_het = off;

    const int threads = 256;
    const int nblocks = (N_NODES + threads - 1) / threads;

    hipMemsetAsync(d_ws, 0, 64, stream);
    prep<<<nblocks, threads, 0, stream>>>(x, u_pred, j1v, Tsrc, Tdst, szh);

    if (ws_size >= need_sort) {
        const bool emit = (ws_size >= need_het);
        k_hist<<<NCHUNK, threads, 0, stream>>>((const v4i*)row_idx, (const v4i*)eattr,
                                               histC, hist_het);
        k_scan1<<<NB, threads, 0, stream>>>(histC, scannedB, total);
        k_scan2<<<2, threads, 0, stream>>>(hist_het, total, hetbase, baseb);
        {
            dim3 g((NCHUNK + 1 + 31) / 32, (NB + 31) / 32);
            k_tr<<<g, 256, 0, stream>>>(scannedB, scannedC);
        }
        if (emit) {
            k_scatter<1><<<NCHUNK, threads, 0, stream>>>(
                (const v4i*)row_idx, (const v4i*)col_idx, (const v4i*)eattr,
                (const v4f*)cdx, (const v4f*)cdy, (const v4f*)clap,
                Tsrc, Tdst, baseb, scannedC, hetbase, rec, het, acc);
        } else {
            k_scatter<0><<<NCHUNK, threads, 0, stream>>>(
                (const v4i*)row_idx, (const v4i*)col_idx, (const v4i*)eattr,
                (const v4f*)cdx, (const v4f*)cdy, (const v4f*)clap,
                Tsrc, Tdst, baseb, scannedC, hetbase, rec, het, acc);
        }
        k_acc<<<NB, 1024, 0, stream>>>(rec, baseb, total, u_pred, szh, pos2, y, source,
                                       a_p, b_p, bm_p, bp_p, Q, acc);
        if (emit) {
            k_pass2c<<<2048, threads, 0, stream>>>(het, hetbase, Q, c_p, bm_p, bp_p, acc);
        } else {
            k_pass2<<<2048, threads, 0, stream>>>((const v4i*)row_idx, (const v4i*)col_idx,
                                                  (const v4i*)eattr, Q, szh,
                                                  c_p, bm_p, bp_p, acc);
        }
    } else {
        float4* rep = (float4*)(base_p + misc_end);
        hipMemsetAsync(rep, 0, (size_t)N_NODES * 16, stream);
        fb_edge1<<<2048, threads, 0, stream>>>(Tsrc, Tdst, cdx, cdy, clap,
                                               row_idx, col_idx, eattr, (float*)rep, acc);
        fb_reduce<<<nblocks, threads, 0, stream>>>(rep, u_pred, szh, pos2, y, source,
                                                   a_p, b_p, bm_p, bp_p, Q, acc);
        k_pass2<<<2048, threads, 0, stream>>>((const v4i*)row_idx, (const v4i*)col_idx,
                                              (const v4i*)eattr, Q, szh,
                                              c_p, bm_p, bp_p, acc);
    }

    finalize<<<1, 64, 0, stream>>>(acc, (float*)d_out);
}

// Round 17
// 374.718 us; speedup vs baseline: 1.0595x; 1.0000x over previous
//
#include <hip/hip_runtime.h>
#include <hip/hip_fp16.h>

#define N_NODES 500000
#define N_EDGES 8000000
#define EPSF 1e-8f

#define WIN_SHIFT 11
#define WINDOW 2048
#define NB 245                       // ceil(500000/2048)
#define CHUNK 8000                   // edges per scatter chunk (runs avg 32.6)
#define NQ (CHUNK / 4)
#define NCHUNK 1000                  // 8e6 / 8000
#define SC_ITEMS 4                   // 256*4 >= NCHUNK

typedef int            v4i __attribute__((ext_vector_type(4)));
typedef float          v4f __attribute__((ext_vector_type(4)));
typedef unsigned short v4h __attribute__((ext_vector_type(4)));
typedef int            v2i __attribute__((ext_vector_type(2)));

struct Accum { double pde_sum, bc_sum, bc_cnt, j1_sum, j2_sum, het_cnt; };

__device__ __forceinline__ unsigned short f2h(float f) {
    return __half_as_ushort(__float2half(f));
}
__device__ __forceinline__ float h2f(unsigned short u) {
    return __half2float(__ushort_as_half(u));
}

// Block-wide f64 sum. Valid on thread 0 only. All threads must call. Supports <=1024 threads.
__device__ double block_reduce(double v) {
    __shared__ double sm[16];
    __syncthreads();
    for (int off = 32; off; off >>= 1) v += __shfl_down(v, off, 64);
    const int lane = threadIdx.x & 63, wid = threadIdx.x >> 6;
    if (lane == 0) sm[wid] = v;
    __syncthreads();
    if (wid == 0) {
        const int nw = blockDim.x >> 6;
        v = (lane < nw) ? sm[lane] : 0.0;
        for (int off = 8; off; off >>= 1) v += __shfl_down(v, off, 64);
    }
    return v;
}

// Exclusive prefix over <=1024 threads. Caller must __syncthreads() before reusing smw.
__device__ unsigned int block_excl_scan_u32(unsigned int x, unsigned int* smw) {
    const int lane = threadIdx.x & 63, wid = threadIdx.x >> 6;
    unsigned int v = x;
    for (int d = 1; d < 64; d <<= 1) {
        unsigned int t = __shfl_up(v, d, 64);
        if (lane >= d) v += t;
    }
    if (lane == 63) smw[wid] = v;
    __syncthreads();
    unsigned int base = 0;
    for (int w = 0; w < wid; ++w) base += smw[w];
    return base + v - x;
}

// Packed endpoint tables (2 MB each, L2-resident):
// Tsrc[i] = uh | (j1h << 16); Tdst[i] = uh | (szh << 16). szh kept for node passes.
__global__ void prep(const float* __restrict__ x, const float* __restrict__ u,
                     const float* __restrict__ j1,
                     unsigned int* __restrict__ Tsrc, unsigned int* __restrict__ Tdst,
                     unsigned short* __restrict__ szh) {
    const int stride = gridDim.x * blockDim.x;
    for (int i = blockIdx.x * blockDim.x + threadIdx.x; i < N_NODES; i += stride) {
        const float z = x[4 * i + 3];
        const unsigned int uhb = f2h(u[i]);
        const unsigned short sb = f2h((float)(z > 0.f) - (float)(z < 0.f));
        Tsrc[i] = uhb | ((unsigned int)f2h(j1[i]) << 16);
        Tdst[i] = uhb | ((unsigned int)sb << 16);
        szh[i]  = sb;
    }
}

// per-chunk bucket histogram + per-chunk het count.
__global__ void k_hist(const v4i* __restrict__ row4, const v4i* __restrict__ attr4,
                       unsigned int* __restrict__ histC,
                       unsigned int* __restrict__ hist_het) {
    __shared__ unsigned int h[NB];
    __shared__ unsigned int hh;
    for (int i = threadIdx.x; i < NB; i += blockDim.x) h[i] = 0;
    if (threadIdx.x == 0) hh = 0;
    __syncthreads();
    const int ch = blockIdx.x;
    unsigned int my = 0;
    for (int q = threadIdx.x; q < NQ; q += blockDim.x) {
        const v4i r = __builtin_nontemporal_load(&row4[ch * NQ + q]);
        const v4i a = __builtin_nontemporal_load(&attr4[ch * NQ + q]);
        atomicAdd(&h[r[0] >> WIN_SHIFT], 1u);
        atomicAdd(&h[r[1] >> WIN_SHIFT], 1u);
        atomicAdd(&h[r[2] >> WIN_SHIFT], 1u);
        atomicAdd(&h[r[3] >> WIN_SHIFT], 1u);
        my += (a[0] == 1) + (a[1] == 1) + (a[2] == 1) + (a[3] == 1);
    }
    if (my) atomicAdd(&hh, my);
    __syncthreads();
    for (int i = threadIdx.x; i < NB; i += blockDim.x)
        histC[(size_t)ch * NB + i] = h[i];
    if (threadIdx.x == 0) hist_het[ch] = hh;
}

// per-bucket exclusive scan across chunks.
__global__ void k_scan1(const unsigned int* __restrict__ histC,
                        unsigned int* __restrict__ scannedB,
                        unsigned int* __restrict__ total) {
    __shared__ unsigned int v[NCHUNK];
    __shared__ unsigned int smw[16];
    const int b = blockIdx.x;
    for (int i = threadIdx.x; i < NCHUNK; i += blockDim.x)
        v[i] = histC[(size_t)i * NB + b];
    __syncthreads();
    const int i0 = threadIdx.x * SC_ITEMS;
    unsigned int s = 0;
    for (int k = 0; k < SC_ITEMS; ++k) { const int i = i0 + k; if (i < NCHUNK) s += v[i]; }
    const unsigned int ex = block_excl_scan_u32(s, smw);
    if (threadIdx.x == blockDim.x - 1) {
        total[b] = ex + s;
        scannedB[(size_t)b * (NCHUNK + 1) + NCHUNK] = ex + s;
    }
    unsigned int run = ex;
    for (int k = 0; k < SC_ITEMS; ++k) {
        const int i = i0 + k;
        if (i < NCHUNK) { scannedB[(size_t)b * (NCHUNK + 1) + i] = run; run += v[i]; }
    }
}

// block 0: het scan -> hetbase[0..NCHUNK]; block 1: bucket-base scan -> baseb.
__global__ void k_scan2(const unsigned int* __restrict__ hist_het,
                        const unsigned int* __restrict__ total,
                        unsigned int* __restrict__ hetbase,
                        unsigned int* __restrict__ baseb) {
    __shared__ unsigned int v[NCHUNK];
    __shared__ unsigned int smw[16];
    if (blockIdx.x == 0) {
        for (int i = threadIdx.x; i < NCHUNK; i += blockDim.x) v[i] = hist_het[i];
        __syncthreads();
        const int i0 = threadIdx.x * SC_ITEMS;
        unsigned int s = 0;
        for (int k = 0; k < SC_ITEMS; ++k) { const int i = i0 + k; if (i < NCHUNK) s += v[i]; }
        const unsigned int ex = block_excl_scan_u32(s, smw);
        if (threadIdx.x == blockDim.x - 1) hetbase[NCHUNK] = ex + s;
        unsigned int run = ex;
        for (int k = 0; k < SC_ITEMS; ++k) {
            const int i = i0 + k;
            if (i < NCHUNK) { hetbase[i] = run; run += v[i]; }
        }
    } else {
        const unsigned int x = (threadIdx.x < NB) ? total[threadIdx.x] : 0;
        const unsigned int ex = block_excl_scan_u32(x, smw);
        if (threadIdx.x < NB) baseb[threadIdx.x] = ex;
    }
}

// tiled transpose: scannedC[ch][b] = scannedB[b][ch].
__global__ void k_tr(const unsigned int* __restrict__ in, unsigned int* __restrict__ out) {
    __shared__ unsigned int t[32][33];
    const int ch0 = blockIdx.x * 32, b0 = blockIdx.y * 32;
    const int tx = threadIdx.x & 31, ty0 = threadIdx.x >> 5;
    for (int j = ty0; j < 32; j += 8) {
        const int b = b0 + j, ch = ch0 + tx;
        if (b < NB && ch < NCHUNK + 1) t[j][tx] = in[(size_t)b * (NCHUNK + 1) + ch];
    }
    __syncthreads();
    for (int j = ty0; j < 32; j += 8) {
        const int ch = ch0 + j, b = b0 + tx;
        if (ch < NCHUNK + 1 && b < NB) out[(size_t)ch * NB + b] = t[tx][j];
    }
}

// LDS-staged bucket-sorted scatter + j1 loss + compacted het list.
// 512 threads, 2 blocks/CU -> 16 waves/CU for MLP.
template<int EMIT_HET>
__global__ void __launch_bounds__(512, 2)
k_scatter(const v4i* __restrict__ row4, const v4i* __restrict__ col4,
          const v4i* __restrict__ attr4,
          const v4f* __restrict__ cdx4, const v4f* __restrict__ cdy4,
          const v4f* __restrict__ clap4,
          const unsigned int* __restrict__ Tsrc, const unsigned int* __restrict__ Tdst,
          const unsigned int* __restrict__ baseb,
          const unsigned int* __restrict__ scannedC,
          const unsigned int* __restrict__ hetbase,
          v4h* __restrict__ rec, v2i* __restrict__ het, Accum* __restrict__ acc) {
    __shared__ int           lcur[NB];
    __shared__ unsigned int  lbase[NB];
    __shared__ unsigned int  gdest[NB];
    __shared__ unsigned int  smw[16];
    __shared__ v4h           o4[CHUNK];
    __shared__ unsigned char obk[CHUNK];
    __shared__ int           hcur;

    const int ch = blockIdx.x;
    unsigned int cnt = 0;
    if (threadIdx.x < NB) {
        const unsigned int s0 = scannedC[(size_t)ch * NB + threadIdx.x];
        const unsigned int s1 = scannedC[(size_t)(ch + 1) * NB + threadIdx.x];
        cnt = s1 - s0;
        gdest[threadIdx.x] = baseb[threadIdx.x] + s0;
        lcur[threadIdx.x] = 0;
    }
    if (EMIT_HET && threadIdx.x == 0) hcur = (int)hetbase[ch];
    const unsigned int exv = block_excl_scan_u32(cnt, smw);
    if (threadIdx.x < NB) lbase[threadIdx.x] = exv;
    __syncthreads();

    double j1s = 0.0;
    int hc = 0;
    for (int q = threadIdx.x; q < NQ; q += blockDim.x) {
        const v4i r4 = __builtin_nontemporal_load(&row4[ch * NQ + q]);
        const v4i c4 = __builtin_nontemporal_load(&col4[ch * NQ + q]);
        const v4i a4 = __builtin_nontemporal_load(&attr4[ch * NQ + q]);
        const v4f cx = __builtin_nontemporal_load(&cdx4[ch * NQ + q]);
        const v4f cy = __builtin_nontemporal_load(&cdy4[ch * NQ + q]);
        const v4f cl = __builtin_nontemporal_load(&clap4[ch * NQ + q]);
#pragma unroll
        for (int k = 0; k < 4; ++k) {
            const int r = r4[k], c = c4[k];
            const unsigned int ts = Tsrc[r];
            const unsigned int td = Tdst[c];
            const float ud = h2f((unsigned short)td) - h2f((unsigned short)ts);
            const int b = r >> WIN_SHIFT;
            const int p = (int)lbase[b] + atomicAdd(&lcur[b], 1);
            v4h rc;
            rc[0] = (unsigned short)(r & (WINDOW - 1));
            rc[1] = f2h(ud * cx[k]);
            rc[2] = f2h(ud * cy[k]);
            rc[3] = f2h(ud * cl[k]);
            o4[p] = rc;
            obk[p] = (unsigned char)b;
            if (a4[k] == 1) {
                const float d = h2f((unsigned short)(td >> 16)) * ud -
                                h2f((unsigned short)(ts >> 16));
                j1s += (double)(d * d);
                hc++;
                if (EMIT_HET) {
                    const int pos = atomicAdd(&hcur, 1);   // LDS counter
                    v2i e; e[0] = r; e[1] = c;
                    __builtin_nontemporal_store(e, &het[pos]);
                }
            }
        }
    }
    __syncthreads();

    for (int i = threadIdx.x; i < CHUNK; i += blockDim.x) {
        const v4h rc = o4[i];
        const int b = obk[i];
        const unsigned int dest = gdest[b] + (unsigned int)(i - (int)lbase[b]);
        __builtin_nontemporal_store(rc, &rec[dest]);
    }

    double t = block_reduce(j1s);
    if (threadIdx.x == 0) atomicAdd(&acc->j1_sum, t);
    t = block_reduce((double)hc);
    if (threadIdx.x == 0) atomicAdd(&acc->het_cnt, t);
}

// Fused per-bucket LDS accumulate at 1024 threads; emit Q with sz in LSBs; pde/bc.
__global__ void __launch_bounds__(1024, 1)
k_acc(const v4h* __restrict__ rec,
      const unsigned int* __restrict__ baseb,
      const unsigned int* __restrict__ total,
      const float* __restrict__ u, const unsigned short* __restrict__ szh,
      const float2* __restrict__ pos2,
      const float* __restrict__ y, const float* __restrict__ source,
      const float* __restrict__ a_p, const float* __restrict__ b_p,
      const float* __restrict__ bm_p, const float* __restrict__ bp_p,
      v4h* __restrict__ Q, Accum* __restrict__ acc) {
    __shared__ float a3[WINDOW * 3];
    for (int i = threadIdx.x; i < WINDOW * 3; i += blockDim.x) a3[i] = 0.f;
    __syncthreads();
    const int b = blockIdx.x;
    const int s = (int)baseb[b];
    const int e = s + (int)total[b];
    for (int i = s + threadIdx.x; i < e; i += blockDim.x) {
        const v4h rc = __builtin_nontemporal_load(&rec[i]);
        const int lr = (int)(rc[0] & (WINDOW - 1)) * 3;
        atomicAdd(&a3[lr + 0], h2f(rc[1]));
        atomicAdd(&a3[lr + 1], h2f(rc[2]));
        atomicAdd(&a3[lr + 2], h2f(rc[3]));
    }
    __syncthreads();
    const float av = a_p[0], bv = b_p[0], bm = bm_p[0], bp = bp_p[0];
    const float ha = 0.5f / (av * av), hb = 0.5f / (bv * bv);
    double pde = 0.0, bcs = 0.0;
    int bcc = 0;
    const int n0 = b << WIN_SHIFT;
    const int n1 = min(n0 + WINDOW, N_NODES);
    for (int i = n0 + threadIdx.x; i < n1; i += blockDim.x) {
        const int l = (i - n0) * 3;
        const float szv = h2f(szh[i]);
        const float beta = (szv < 0.f) ? bm : bp;
        const float2 p = pos2[i];
        v4h qo;
        qo[0] = f2h(p.x * ha);
        qo[1] = f2h(p.y * hb);
        qo[2] = (unsigned short)((f2h(beta * a3[l]) & 0xFFFEu) | (szv < 0.f ? 1u : 0u));
        qo[3] = (unsigned short)((f2h(beta * a3[l + 1]) & 0xFFFEu) | (szv == 0.f ? 1u : 0u));
        Q[i] = qo;
        const float res = -a3[l + 2] - source[i] / beta;
        pde += (double)(res * res);
        if (fabsf(p.x) > 0.99f || fabsf(p.y) > 0.99f) {
            const float d = u[i] - y[i];
            bcs += (double)(d * d);
            bcc++;
        }
    }
    double t = block_reduce(pde);
    if (threadIdx.x == 0) atomicAdd(&acc->pde_sum, t);
    t = block_reduce(bcs);
    if (threadIdx.x == 0) atomicAdd(&acc->bc_sum, t);
    t = block_reduce((double)bcc);
    if (threadIdx.x == 0) atomicAdd(&acc->bc_cnt, t);
}

// j2 over compacted het list: 8B stream + exactly two 8B Q gathers per edge.
__global__ void k_pass2c(const v2i* __restrict__ het,
                         const unsigned int* __restrict__ hetbase,
                         const v4h* __restrict__ Q,
                         const float* __restrict__ c_p,
                         const float* __restrict__ bm_p, const float* __restrict__ bp_p,
                         Accum* __restrict__ acc) {
    const float tgt = 2.f * (c_p[0] * bp_p[0] - bm_p[0]);
    const int tot = (int)hetbase[NCHUNK];
    double j2s = 0.0;
    const int stride = gridDim.x * blockDim.x;
    for (int i = blockIdx.x * blockDim.x + threadIdx.x; i < tot; i += stride) {
        const v2i e = __builtin_nontemporal_load(&het[i]);
        const v4h qr = Q[e[0]];
        const v4h qc = Q[e[1]];
        const float nx = h2f(qr[0]) + h2f(qc[0]);
        const float ny = h2f(qr[1]) + h2f(qc[1]);
        const float nrm = fmaxf(sqrtf(nx * nx + ny * ny), EPSF);
        const float B = ((h2f(qc[2]) - h2f(qr[2])) * nx +
                         (h2f(qc[3]) - h2f(qr[3])) * ny) / nrm;
        const float sz = (qc[3] & 1u) ? 0.f : ((qc[2] & 1u) ? -1.f : 1.f);
        const float d = sz * B - tgt * nrm;
        j2s += (double)(d * d);
    }
    const double t = block_reduce(j2s);
    if (threadIdx.x == 0) atomicAdd(&acc->j2_sum, t);
}

// j2 over raw edges (fallback tier).
__global__ void k_pass2(const v4i* __restrict__ row4, const v4i* __restrict__ col4,
                        const v4i* __restrict__ attr4,
                        const v4h* __restrict__ Q, const unsigned short* __restrict__ szh,
                        const float* __restrict__ c_p,
                        const float* __restrict__ bm_p, const float* __restrict__ bp_p,
                        Accum* __restrict__ acc) {
    const float tgt = 2.f * (c_p[0] * bp_p[0] - bm_p[0]);
    double j2s = 0.0;
    const int stride = gridDim.x * blockDim.x;
    const int NQT = N_EDGES / 4;
    for (int q = blockIdx.x * blockDim.x + threadIdx.x; q < NQT; q += stride) {
        const v4i r4 = __builtin_nontemporal_load(&row4[q]);
        const v4i c4 = __builtin_nontemporal_load(&col4[q]);
        const v4i a4 = __builtin_nontemporal_load(&attr4[q]);
#pragma unroll
        for (int k = 0; k < 4; ++k) {
            if (a4[k] != 1) continue;
            const int r = r4[k], c = c4[k];
            const v4h qr = Q[r];
            const v4h qc = Q[c];
            const float nx = h2f(qr[0]) + h2f(qc[0]);
            const float ny = h2f(qr[1]) + h2f(qc[1]);
            const float nrm = fmaxf(sqrtf(nx * nx + ny * ny), EPSF);
            const float B = ((h2f(qc[2]) - h2f(qr[2])) * nx +
                             (h2f(qc[3]) - h2f(qr[3])) * ny) / nrm;
            const float d = h2f(szh[c]) * B - tgt * nrm;
            j2s += (double)(d * d);
        }
    }
    const double t = block_reduce(j2s);
    if (threadIdx.x == 0) atomicAdd(&acc->j2_sum, t);
}

// ---------------- fallback (small ws): device atomics ----------------
__global__ void fb_edge1(const unsigned int* __restrict__ Tsrc,
                         const unsigned int* __restrict__ Tdst,
                         const float* __restrict__ cdx, const float* __restrict__ cdy,
                         const float* __restrict__ clap,
                         const int* __restrict__ row, const int* __restrict__ col,
                         const int* __restrict__ attr,
                         float* __restrict__ rep, Accum* __restrict__ acc) {
    double j1s = 0.0;
    int hc = 0;
    const int stride = gridDim.x * blockDim.x;
    for (int e = blockIdx.x * blockDim.x + threadIdx.x; e < N_EDGES; e += stride) {
        const int r = row[e], c = col[e];
        const unsigned int ts = Tsrc[r];
        const unsigned int td = Tdst[c];
        const float ud = h2f((unsigned short)td) - h2f((unsigned short)ts);
        atomicAdd(&rep[4 * (size_t)r + 0], ud * cdx[e]);
        atomicAdd(&rep[4 * (size_t)r + 1], ud * cdy[e]);
        atomicAdd(&rep[4 * (size_t)r + 2], ud * clap[e]);
        if (attr[e] == 1) {
            const float d = h2f((unsigned short)(td >> 16)) * ud -
                            h2f((unsigned short)(ts >> 16));
            j1s += (double)(d * d);
            hc++;
        }
    }
    double t = block_reduce(j1s);
    if (threadIdx.x == 0) atomicAdd(&acc->j1_sum, t);
    t = block_reduce((double)hc);
    if (threadIdx.x == 0) atomicAdd(&acc->het_cnt, t);
}

__global__ void fb_reduce(const float4* __restrict__ rep,
                          const float* __restrict__ u, const unsigned short* __restrict__ szh,
                          const float2* __restrict__ pos2,
                          const float* __restrict__ y, const float* __restrict__ source,
                          const float* __restrict__ a_p, const float* __restrict__ b_p,
                          const float* __restrict__ bm_p, const float* __restrict__ bp_p,
                          v4h* __restrict__ Q, Accum* __restrict__ acc) {
    const float av = a_p[0], bv = b_p[0], bm = bm_p[0], bp = bp_p[0];
    const float ha = 0.5f / (av * av), hb = 0.5f / (bv * bv);
    double pde = 0.0, bcs = 0.0;
    int bcc = 0;
    const int stride = gridDim.x * blockDim.x;
    for (int i = blockIdx.x * blockDim.x + threadIdx.x; i < N_NODES; i += stride) {
        const float4 v = rep[i];
        const float szv = h2f(szh[i]);
        const float beta = (szv < 0.f) ? bm : bp;
        const float2 p = pos2[i];
        v4h qo;
        qo[0] = f2h(p.x * ha);
        qo[1] = f2h(p.y * hb);
        qo[2] = (unsigned short)((f2h(beta * v.x) & 0xFFFEu) | (szv < 0.f ? 1u : 0u));
        qo[3] = (unsigned short)((f2h(beta * v.y) & 0xFFFEu) | (szv == 0.f ? 1u : 0u));
        Q[i] = qo;
        const float res = -v.z - source[i] / beta;
        pde += (double)(res * res);
        if (fabsf(p.x) > 0.99f || fabsf(p.y) > 0.99f) {
            const float d = u[i] - y[i];
            bcs += (double)(d * d);
            bcc++;
        }
    }
    double t = block_reduce(pde);
    if (threadIdx.x == 0) atomicAdd(&acc->pde_sum, t);
    t = block_reduce(bcs);
    if (threadIdx.x == 0) atomicAdd(&acc->bc_sum, t);
    t = block_reduce((double)bcc);
    if (threadIdx.x == 0) atomicAdd(&acc->bc_cnt, t);
}

__global__ void finalize(const Accum* __restrict__ acc, float* __restrict__ out) {
    if (threadIdx.x == 0 && blockIdx.x == 0) {
        const double loss_pde = acc->pde_sum / (double)N_NODES;
        const double loss_bc  = acc->bc_sum / fmax(acc->bc_cnt, 1.0);
        const double hc       = fmax(acc->het_cnt, 1.0);
        out[0] = (float)(loss_pde + 100.0 * loss_bc +
                         10.0 * (acc->j1_sum / hc) + 10.0 * (acc->j2_sum / hc));
    }
}

extern "C" void kernel_launch(void* const* d_in, const int* in_sizes, int n_in,
                              void* d_out, int out_size, void* d_ws, size_t ws_size,
                              hipStream_t stream) {
    const float* u_pred = (const float*)d_in[0];
    const float* x      = (const float*)d_in[1];
    const float2* pos2  = (const float2*)d_in[2];
    const float* y      = (const float*)d_in[3];
    const float* source = (const float*)d_in[4];
    const float* j1v    = (const float*)d_in[5];
    const float* cdx    = (const float*)d_in[6];
    const float* cdy    = (const float*)d_in[7];
    const float* clap   = (const float*)d_in[8];
    const float* a_p    = (const float*)d_in[9];
    const float* b_p    = (const float*)d_in[10];
    const float* c_p    = (const float*)d_in[11];
    const float* bm_p   = (const float*)d_in[12];
    const float* bp_p   = (const float*)d_in[13];
    const int* row_idx  = (const int*)d_in[14];
    const int* col_idx  = row_idx + N_EDGES;
    const int* eattr    = (const int*)d_in[15];

    char* base_p = (char*)d_ws;
    size_t off = 0;
    auto alloc = [&](size_t bytes) { void* p = base_p + off; off = (off + bytes + 63) & ~(size_t)63; return p; };

    Accum* acc = (Accum*)alloc(sizeof(Accum));
    unsigned int* Tsrc = (unsigned int*)alloc((size_t)N_NODES * 4);
    unsigned int* Tdst = (unsigned int*)alloc((size_t)N_NODES * 4);
    unsigned short* szh = (unsigned short*)alloc((size_t)N_NODES * 2);
    v4h* Q = (v4h*)alloc((size_t)N_NODES * 8);
    unsigned int* histC    = (unsigned int*)alloc((size_t)(NCHUNK + 1) * NB * 4);
    unsigned int* scannedB = (unsigned int*)alloc((size_t)NB * (NCHUNK + 1) * 4);
    unsigned int* total    = (unsigned int*)alloc(NB * 4);
    unsigned int* baseb    = (unsigned int*)alloc(NB * 4);
    unsigned int* hist_het = (unsigned int*)alloc((size_t)NCHUNK * 4);
    unsigned int* hetbase  = (unsigned int*)alloc((size_t)(NCHUNK + 1) * 4);
    unsigned int* scannedC = histC;          // safe: k_scan1 consumes histC before k_tr writes
    const size_t misc_end = off;
    v4h* rec = (v4h*)alloc((size_t)N_EDGES * 8);
    const size_t need_sort = off;
    v2i* het = (v2i*)alloc((size_t)N_EDGES * 8);   // capacity = all edges: no overflow
    const size_t need_het = off;

    const int threads = 256;
    const int nblocks = (N_NODES + threads - 1) / threads;

    hipMemsetAsync(d_ws, 0, 64, stream);
    prep<<<nblocks, threads, 0, stream>>>(x, u_pred, j1v, Tsrc, Tdst, szh);

    if (ws_size >= need_sort) {
        const bool emit = (ws_size >= need_het);
        k_hist<<<NCHUNK, threads, 0, stream>>>((const v4i*)row_idx, (const v4i*)eattr,
                                               histC, hist_het);
        k_scan1<<<NB, threads, 0, stream>>>(histC, scannedB, total);
        k_scan2<<<2, threads, 0, stream>>>(hist_het, total, hetbase, baseb);
        {
            dim3 g((NCHUNK + 1 + 31) / 32, (NB + 31) / 32);
            k_tr<<<g, 256, 0, stream>>>(scannedB, scannedC);
        }
        if (emit) {
            k_scatter<1><<<NCHUNK, 512, 0, stream>>>(
                (const v4i*)row_idx, (const v4i*)col_idx, (const v4i*)eattr,
                (const v4f*)cdx, (const v4f*)cdy, (const v4f*)clap,
                Tsrc, Tdst, baseb, scannedC, hetbase, rec, het, acc);
        } else {
            k_scatter<0><<<NCHUNK, 512, 0, stream>>>(
                (const v4i*)row_idx, (const v4i*)col_idx, (const v4i*)eattr,
                (const v4f*)cdx, (const v4f*)cdy, (const v4f*)clap,
                Tsrc, Tdst, baseb, scannedC, hetbase, rec, het, acc);
        }
        k_acc<<<NB, 1024, 0, stream>>>(rec, baseb, total, u_pred, szh, pos2, y, source,
                                       a_p, b_p, bm_p, bp_p, Q, acc);
        if (emit) {
            k_pass2c<<<2048, threads, 0, stream>>>(het, hetbase, Q, c_p, bm_p, bp_p, acc);
        } else {
            k_pass2<<<2048, threads, 0, stream>>>((const v4i*)row_idx, (const v4i*)col_idx,
                                                  (const v4i*)eattr, Q, szh,
                                                  c_p, bm_p, bp_p, acc);
        }
    } else {
        float4* rep = (float4*)(base_p + misc_end);
        hipMemsetAsync(rep, 0, (size_t)N_NODES * 16, stream);
        fb_edge1<<<2048, threads, 0, stream>>>(Tsrc, Tdst, cdx, cdy, clap,
                                               row_idx, col_idx, eattr, (float*)rep, acc);
        fb_reduce<<<nblocks, threads, 0, stream>>>(rep, u_pred, szh, pos2, y, source,
                                                   a_p, b_p, bm_p, bp_p, Q, acc);
        k_pass2<<<2048, threads, 0, stream>>>((const v4i*)row_idx, (const v4i*)col_idx,
                                              (const v4i*)eattr, Q, szh,
                                              c_p, bm_p, bp_p, acc);
    }

    finalize<<<1, 64, 0, stream>>>(acc, (float*)d_out);
}